// Round 8
// baseline (138.737 us; speedup 1.0000x reference)
//
#include <hip/hip_runtime.h>
#include <hip/hip_bf16.h>
#include <math.h>

#define Bn 2048
#define Dn 512
#define Cn 16384

typedef __bf16 v8bf __attribute__((ext_vector_type(8)));
typedef float v4f __attribute__((ext_vector_type(4)));

#define WAIT_VM6()  asm volatile("s_waitcnt vmcnt(6)" ::: "memory")
#define WAIT_VM0()  asm volatile("s_waitcnt vmcnt(0)" ::: "memory")
#define RAW_BAR()   asm volatile("s_barrier" ::: "memory")
#define LGKM0_BAR() asm volatile("s_waitcnt lgkmcnt(0)\n\ts_barrier" ::: "memory")

__device__ __forceinline__ void async16(const void* g, void* l) {
  __builtin_amdgcn_global_load_lds(
      (const __attribute__((address_space(1))) char*)g,
      (__attribute__((address_space(3))) char*)l, 16, 0, 0);
}

// ---------------- prep: wave-per-row norms, scales, bf16 conversion ----------------
__global__ __launch_bounds__(256) void prep_kernel(
    const float* __restrict__ w, const float* __restrict__ x,
    __hip_bfloat16* __restrict__ wbf, __hip_bfloat16* __restrict__ xbf,
    float* __restrict__ fscale, float* __restrict__ ysqA, float* __restrict__ yrA,
    float* __restrict__ xsA, float* __restrict__ xrA)
{
  int gw = (blockIdx.x * 256 + threadIdx.x) >> 6;  // wave id == row
  int lane = threadIdx.x & 63;
  bool isW = gw < Cn;
  const float* src = isW ? (w + (size_t)gw * Dn) : (x + (size_t)(gw - Cn) * Dn);
  const float4* s4 = (const float4*)src;
  float4 a = s4[lane * 2], b = s4[lane * 2 + 1];  // 32 B/lane, coalesced
  float ss = a.x * a.x + a.y * a.y + a.z * a.z + a.w * a.w
           + b.x * b.x + b.y * b.y + b.z * b.z + b.w * b.w;
  #pragma unroll
  for (int d = 1; d < 64; d <<= 1) ss += __shfl_xor(ss, d);

  union { __hip_bfloat16 h[8]; int4 i4; } u;
  u.h[0] = __float2bfloat16(a.x); u.h[1] = __float2bfloat16(a.y);
  u.h[2] = __float2bfloat16(a.z); u.h[3] = __float2bfloat16(a.w);
  u.h[4] = __float2bfloat16(b.x); u.h[5] = __float2bfloat16(b.y);
  u.h[6] = __float2bfloat16(b.z); u.h[7] = __float2bfloat16(b.w);
  __hip_bfloat16* dst = isW ? (wbf + (size_t)gw * Dn) : (xbf + (size_t)(gw - Cn) * Dn);
  ((int4*)dst)[lane] = u.i4;  // 16 B/lane, coalesced

  if (lane == 0) {
    if (isW) {
      float n = fmaxf(sqrtf(ss), 1e-7f);
      float t = tanhf(n);           // c=1: tanh(sqrt_c * norm)
      float tc = fminf(t, 0.95f);   // radius clip folded into scale
      fscale[gw] = tc / n;          // proto = fscale * w
      float ys = tc * tc;           // ||proto||^2
      ysqA[gw] = ys;
      yrA[gw] = 1.f / (1.f - fminf(ys, 1.f - 1e-5f));
    } else {
      int r = gw - Cn;
      xsA[r] = ss;
      xrA[r] = 1.f / (1.f - fminf(ss, 1.f - 1e-5f));
    }
  }
}

// ------- bf16 MFMA GEMM: 128x256 block, 64x128 wave tiles, vmcnt pipeline -------
// R8 change: iteration order is reads -> MFMA -> lgkm0+barrier -> prefetch.
// R7 had LGKM0_BAR between reads and MFMA, forcing every wave to drain ALL 12
// ds_reads (~250 cyc) before its first MFMA and re-coupling waves -- measured
// per-iter wall ~3900 cyc vs ~1150 max-pipe. With the drain moved after the
// MFMAs, the compiler interleaves fine lgkmcnt(N) waits (MFMA starts when
// af[0]/bfv[0] land) and the barrier's lgkm drain is trivially satisfied.
// Buffer safety unchanged: all waves' reads of buf[cur] complete at the
// barrier before tile kt+2's loads are issued into it; vmcnt(6) at iter top
// still drains exactly loads(kt) while loads(kt+1) stay in flight.
__global__ __launch_bounds__(256, 2) void gemm_kernel(
    const __hip_bfloat16* __restrict__ xbf, const __hip_bfloat16* __restrict__ wbf,
    const float* __restrict__ fscale, const float* __restrict__ ysqA,
    const float* __restrict__ yrA, const float* __restrict__ xsA,
    const float* __restrict__ xrA, float* __restrict__ partials)
{
  __shared__ int4 ldsv[3072];  // 48 KB: buf{0,1} x [A 8K][W 16K]
  char* lds = (char*)ldsv;

  const int bid = blockIdx.x;           // 1024 blocks
  const int xcd = bid & 7;              // round-robin dispatch across XCDs
  const int loc = bid >> 3;             // 0..127
  const int mt  = loc & 15;             // 16 m-tiles of 128 (m fastest: share W band)
  const int nt  = (xcd << 3) | (loc >> 4);  // 64 n-tiles of 256, banded per XCD
  const int mBase = mt * 128;
  const int nBase = nt * 256;
  const int tid = threadIdx.x;
  const int lane = tid & 63;
  const int wave = tid >> 6;
  const int quad = lane >> 4;
  const int l16 = lane & 15;
  const int waveM = wave >> 1;          // 2 x 64 rows
  const int waveN = wave & 1;           // 2 x 128 cols

  v4f acc[4][8];
  #pragma unroll
  for (int i = 0; i < 4; ++i)
    #pragma unroll
    for (int j = 0; j < 8; ++j)
      acc[i][j] = (v4f){0.f, 0.f, 0.f, 0.f};

  // staging. A tile: 128 rows x 64 B = 512 chunks (2/thread); W: 256 rows = 1024
  // chunks (4/thread). slot s: r=s>>2, slot-col s&3, global col (s&3)^((r>>1)&3).
  const int sA0 = tid, sA1 = tid + 256;
  const int rA0 = sA0 >> 2, cA0 = (sA0 & 3) ^ ((rA0 >> 1) & 3);
  const int rA1 = sA1 >> 2, cA1 = (sA1 & 3) ^ ((rA1 >> 1) & 3);
  const char* gA0 = (const char*)xbf + (size_t)(mBase + rA0) * (Dn * 2) + cA0 * 16;
  const char* gA1 = (const char*)xbf + (size_t)(mBase + rA1) * (Dn * 2) + cA1 * 16;
  const int loA0 = sA0 * 16, loA1 = sA1 * 16;
  const char* gW[4]; int loW[4];
  #pragma unroll
  for (int p = 0; p < 4; ++p) {
    int s = tid + p * 256;
    int r = s >> 2, c = (s & 3) ^ ((r >> 1) & 3);
    gW[p] = (const char*)wbf + (size_t)(nBase + r) * (Dn * 2) + c * 16;
    loW[p] = s * 16;
  }

  // frag read offsets (swizzle-aware), relative to A / W region bases
  int aoffs[4], boffs[8];
  #pragma unroll
  for (int i = 0; i < 4; ++i) {
    int ra = waveM * 64 + i * 16 + l16;
    aoffs[i] = ra * 64 + ((quad ^ ((ra >> 1) & 3)) * 16);
  }
  #pragma unroll
  for (int j = 0; j < 8; ++j) {
    int rb = waveN * 128 + j * 16 + l16;
    boffs[j] = rb * 64 + ((quad ^ ((rb >> 1) & 3)) * 16);
  }

  // prologue: tiles 0,1 -> buffers 0,1 (12 loads in flight per thread)
  #pragma unroll
  for (int t = 0; t < 2; ++t) {
    char* Ab = lds + t * 24576;
    char* Wb = Ab + 8192;
    async16(gA0 + t * 64, Ab + loA0);
    async16(gA1 + t * 64, Ab + loA1);
    #pragma unroll
    for (int p = 0; p < 4; ++p) async16(gW[p] + t * 64, Wb + loW[p]);
  }

  #pragma unroll
  for (int kt = 0; kt < 16; ++kt) {
    const int cur = kt & 1;
    if (kt < 15) { WAIT_VM6(); } else { WAIT_VM0(); }  // buf[cur]'s 6 loads landed
    RAW_BAR();                                          // ...for ALL waves
    char* Ab = lds + cur * 24576;
    char* Wb = Ab + 8192;
    v8bf af[4], bfv[8];
    #pragma unroll
    for (int i = 0; i < 4; ++i) af[i] = *(const v8bf*)(Ab + aoffs[i]);
    #pragma unroll
    for (int j = 0; j < 8; ++j) bfv[j] = *(const v8bf*)(Wb + boffs[j]);
    // MFMAs directly after reads: compiler interleaves fine lgkmcnt(N) waits
    #pragma unroll
    for (int i = 0; i < 4; ++i)
      #pragma unroll
      for (int j = 0; j < 8; ++j)
        acc[i][j] = __builtin_amdgcn_mfma_f32_16x16x32_bf16(af[i], bfv[j], acc[i][j], 0, 0, 0);
    LGKM0_BAR();  // all waves' reads of buf[cur] done -> safe to rewrite it
    if (kt + 2 < 16) {  // tile kt+2 into buf[cur]: ~1.5 iters of flight
      async16(gA0 + (kt + 2) * 64, Ab + loA0);
      async16(gA1 + (kt + 2) * 64, Ab + loA1);
      #pragma unroll
      for (int p = 0; p < 4; ++p) async16(gW[p] + (kt + 2) * 64, Wb + loW[p]);
    }
  }

  // ---- epilogue: partial sums of e^{u}, u = 128*sims (e^{+64}-scaled) ----
  float ysqj[8], yrj[8], gj[8];
  #pragma unroll
  for (int j = 0; j < 8; ++j) {
    int col = nBase + waveN * 128 + j * 16 + l16;
    gj[j] = -2.f * fscale[col];
    ysqj[j] = ysqA[col];
    yrj[j] = yrA[col];
  }
  #pragma unroll
  for (int i = 0; i < 4; ++i) {
    #pragma unroll
    for (int r = 0; r < 4; ++r) {
      int row = mBase + waveM * 64 + i * 16 + quad * 4 + r;
      float xs = xsA[row];
      float xr2 = 2.f * xrA[row];
      float partial = 0.f;
      if (xs >= 0.99999f) {
        // clipped row: xr=1e5 -> z large -> u=64/z small.
        // sims~=1/(2z) (rel err 1/(4z^2)); e^u ~= 1+u+u^2/2 (err u^3/6).
        #pragma unroll
        for (int j = 0; j < 8; ++j) {
          float d = fmaxf(fmaf(gj[j], acc[i][j][r], xs + ysqj[j]), 0.f);
          float z = fmaf(d, xr2 * yrj[j], 1.f);
          float u = 64.f * __builtin_amdgcn_rcpf(z);
          partial += fmaf(u, fmaf(0.5f, u, 1.f), 1.f);
        }
      } else {
        // rare unclipped row: exact path
        #pragma unroll
        for (int j = 0; j < 8; ++j) {
          float d = fmaxf(fmaf(gj[j], acc[i][j][r], xs + ysqj[j]), 0.f);
          float z = fmaf(d, xr2 * yrj[j], 1.f);
          float sq = sqrtf(fmaf(z, z, -1.f));
          float u = 128.f * __builtin_amdgcn_rcpf(z + sq);
          partial += __expf(u);
        }
      }
      partial += __shfl_xor(partial, 1);
      partial += __shfl_xor(partial, 2);
      partial += __shfl_xor(partial, 4);
      partial += __shfl_xor(partial, 8);
      if (l16 == 0) partials[(size_t)row * 128 + nt * 2 + waveN] = partial;
    }
  }
}

// ---------------- final: label fix + row term + grid mean (atomic) ----------------
// partials are e^{+64}-scaled: S = sum_j e^{u_j}. term = -64 + log(S - e^{u_lab}
// + e^{64(phi+1)}) - 64*phi.
__global__ __launch_bounds__(256) void final_kernel(
    const float* __restrict__ x, const float* __restrict__ w,
    const int* __restrict__ labels, const float* __restrict__ fscale,
    const float* __restrict__ ysqA, const float* __restrict__ yrA,
    const float* __restrict__ xsA, const float* __restrict__ xrA,
    const float* __restrict__ partials, float* __restrict__ out)
{
  int row = blockIdx.x * 4 + (threadIdx.x >> 6);  // wave per row
  int lane = threadIdx.x & 63;
  const float* pr = partials + (size_t)row * 128;
  float sum = pr[lane] + pr[lane + 64];

  int lab = labels[row];
  const float4* xv = (const float4*)(x + (size_t)row * Dn);
  const float4* wv = (const float4*)(w + (size_t)lab * Dn);
  float4 a0 = xv[lane * 2], a1 = xv[lane * 2 + 1];
  float4 b0 = wv[lane * 2], b1 = wv[lane * 2 + 1];
  float dot = a0.x * b0.x + a0.y * b0.y + a0.z * b0.z + a0.w * b0.w
            + a1.x * b1.x + a1.y * b1.y + a1.z * b1.z + a1.w * b1.w;
  #pragma unroll
  for (int d = 1; d < 64; d <<= 1) {
    sum += __shfl_xor(sum, d);
    dot += __shfl_xor(dot, d);
  }

  __shared__ float red[4];
  if (lane == 0) {
    float xy = fscale[lab] * dot;  // fp32 exact label logit
    float diff = fmaxf(xsA[row] + ysqA[lab] - 2.f * xy, 0.f);
    float z = fmaf(2.f * diff, xrA[row] * yrA[lab], 1.f);
    float sq = sqrtf(fmaf(z, z, -1.f));
    float sims = 1.f / (z + sq);
    float u_lab = 128.f * sims;
    float cosv = fmaf(2.f, sims, -1.f);
    float sine = sqrtf(fmaxf(fmaf(-cosv, cosv, 1.f), 1e-7f));
    float phi = (cosv > -0.8775825619f)
                    ? (cosv * 0.8775825619f - sine * 0.4794255386f)
                    : (cosv - 0.2397127693f);
    float e_lab = __expf(u_lab);                          // e^{+64}-scaled cos term
    float e_phi = __expf(fminf(64.f * phi + 64.f, 80.f)); // scaled margin term
    red[threadIdx.x >> 6] = logf(sum - e_lab + e_phi) - 64.f * phi - 64.f;
  }
  __syncthreads();
  if (threadIdx.x == 0)
    atomicAdd(out, (red[0] + red[1] + red[2] + red[3]) * (1.f / (float)Bn));
}

extern "C" void kernel_launch(void* const* d_in, const int* in_sizes, int n_in,
                              void* d_out, int out_size, void* d_ws, size_t ws_size,
                              hipStream_t stream) {
  (void)in_sizes; (void)n_in; (void)out_size; (void)ws_size;
  const float* emb = (const float*)d_in[0];
  const int* labels = (const int*)d_in[1];
  const float* weight = (const float*)d_in[2];
  float* out = (float*)d_out;

  char* p = (char*)d_ws;
  __hip_bfloat16* wbf = (__hip_bfloat16*)p; p += (size_t)Cn * Dn * 2;  // 16 MB
  __hip_bfloat16* xbf = (__hip_bfloat16*)p; p += (size_t)Bn * Dn * 2;  // 2 MB
  float* fscale = (float*)p; p += (size_t)Cn * 4;
  float* ysqA  = (float*)p; p += (size_t)Cn * 4;
  float* yrA   = (float*)p; p += (size_t)Cn * 4;
  float* xsA   = (float*)p; p += (size_t)Bn * 4;
  float* xrA   = (float*)p; p += (size_t)Bn * 4;
  float* partials = (float*)p; p += (size_t)Bn * 128 * 4;  // 1 MB, written-once

  hipMemsetAsync(out, 0, sizeof(float), stream);  // atomicAdd target
  prep_kernel<<<(Cn + Bn) / 4, 256, 0, stream>>>(weight, emb, wbf, xbf, fscale, ysqA, yrA, xsA, xrA);
  gemm_kernel<<<(Bn / 128) * (Cn / 256), 256, 0, stream>>>(
      xbf, wbf, fscale, ysqA, yrA, xsA, xrA, partials);
  final_kernel<<<Bn / 4, 256, 0, stream>>>(emb, weight, labels, fscale, ysqA, yrA, xsA, xrA, partials, out);
}

// Round 9
// 136.691 us; speedup vs baseline: 1.0150x; 1.0150x over previous
//
#include <hip/hip_runtime.h>
#include <hip/hip_bf16.h>
#include <math.h>

#define Bn 2048
#define Dn 512
#define Cn 16384

typedef __bf16 v8bf __attribute__((ext_vector_type(8)));
typedef float v4f __attribute__((ext_vector_type(4)));

#define WAIT_VM6()  asm volatile("s_waitcnt vmcnt(6)" ::: "memory")
#define WAIT_VM0()  asm volatile("s_waitcnt vmcnt(0)" ::: "memory")
#define LGKM0_BAR() asm volatile("s_waitcnt lgkmcnt(0)\n\ts_barrier" ::: "memory")

__device__ __forceinline__ void async16(const void* g, void* l) {
  __builtin_amdgcn_global_load_lds(
      (const __attribute__((address_space(1))) char*)g,
      (__attribute__((address_space(3))) char*)l, 16, 0, 0);
}

// ---------------- prep: wave-per-row norms, scales, bf16 conversion ----------------
__global__ __launch_bounds__(256) void prep_kernel(
    const float* __restrict__ w, const float* __restrict__ x,
    __hip_bfloat16* __restrict__ wbf, __hip_bfloat16* __restrict__ xbf,
    float* __restrict__ fscale, float* __restrict__ ysqA, float* __restrict__ yrA,
    float* __restrict__ xsA, float* __restrict__ xrA)
{
  int gw = (blockIdx.x * 256 + threadIdx.x) >> 6;  // wave id == row
  int lane = threadIdx.x & 63;
  bool isW = gw < Cn;
  const float* src = isW ? (w + (size_t)gw * Dn) : (x + (size_t)(gw - Cn) * Dn);
  const float4* s4 = (const float4*)src;
  float4 a = s4[lane * 2], b = s4[lane * 2 + 1];  // 32 B/lane, coalesced
  float ss = a.x * a.x + a.y * a.y + a.z * a.z + a.w * a.w
           + b.x * b.x + b.y * b.y + b.z * b.z + b.w * b.w;
  #pragma unroll
  for (int d = 1; d < 64; d <<= 1) ss += __shfl_xor(ss, d);

  union { __hip_bfloat16 h[8]; int4 i4; } u;
  u.h[0] = __float2bfloat16(a.x); u.h[1] = __float2bfloat16(a.y);
  u.h[2] = __float2bfloat16(a.z); u.h[3] = __float2bfloat16(a.w);
  u.h[4] = __float2bfloat16(b.x); u.h[5] = __float2bfloat16(b.y);
  u.h[6] = __float2bfloat16(b.z); u.h[7] = __float2bfloat16(b.w);
  __hip_bfloat16* dst = isW ? (wbf + (size_t)gw * Dn) : (xbf + (size_t)(gw - Cn) * Dn);
  ((int4*)dst)[lane] = u.i4;  // 16 B/lane, coalesced

  if (lane == 0) {
    if (isW) {
      float n = fmaxf(sqrtf(ss), 1e-7f);
      float t = tanhf(n);           // c=1: tanh(sqrt_c * norm)
      float tc = fminf(t, 0.95f);   // radius clip folded into scale
      fscale[gw] = tc / n;          // proto = fscale * w
      float ys = tc * tc;           // ||proto||^2
      ysqA[gw] = ys;
      yrA[gw] = 1.f / (1.f - fminf(ys, 1.f - 1e-5f));
    } else {
      int r = gw - Cn;
      xsA[r] = ss;
      xrA[r] = 1.f / (1.f - fminf(ss, 1.f - 1e-5f));
    }
  }
}

// ------- bf16 MFMA GEMM: 128x256 block, 3-buffer LDS, ONE barrier per iter -------
// R9 change: triple-buffered LDS collapses the two per-iter barriers into one.
// Order: WAIT_VM -> lgkmcnt(0)+s_barrier -> prefetch kt+2 -> ds_read cur ->
// MFMA. The single barrier certifies BOTH "tile kt's DMA landed for all
// waves" (each wave did WAIT_VM before arriving) AND "all waves' iter-(kt-1)
// reads drained" (lgkmcnt(0) before arriving). Prefetch target buf[(kt+2)%3]
// is the buffer read in iter kt-1 -- exactly what the barrier just cleared;
// it is neither cur (kt%3) nor the next iter's buffer ((kt+1)%3), so no
// own-wave DMA-vs-ds_read hazard. vmcnt ledger: prologue primes tiles 0,1
// (12 loads); at iter kt top outstanding = tiles kt,kt+1 (12) -> vmcnt(6)
// drains exactly tile kt; kt=15 drains the last with vmcnt(0).
// Barriers per block: 16 (was 32). LDS 3x24KB=72KB -> 2 blocks/CU.
__global__ __launch_bounds__(256, 2) void gemm_kernel(
    const __hip_bfloat16* __restrict__ xbf, const __hip_bfloat16* __restrict__ wbf,
    const float* __restrict__ fscale, const float* __restrict__ ysqA,
    const float* __restrict__ yrA, const float* __restrict__ xsA,
    const float* __restrict__ xrA, float* __restrict__ partials)
{
  __shared__ int4 ldsv[4608];  // 72 KB: buf{0,1,2} x [A 8K][W 16K]
  char* lds = (char*)ldsv;

  const int bid = blockIdx.x;           // 1024 blocks
  const int xcd = bid & 7;              // round-robin dispatch across XCDs
  const int loc = bid >> 3;             // 0..127
  const int mt  = loc & 15;             // 16 m-tiles of 128 (m fastest: share W band)
  const int nt  = (xcd << 3) | (loc >> 4);  // 64 n-tiles of 256, banded per XCD
  const int mBase = mt * 128;
  const int nBase = nt * 256;
  const int tid = threadIdx.x;
  const int lane = tid & 63;
  const int wave = tid >> 6;
  const int quad = lane >> 4;
  const int l16 = lane & 15;
  const int waveM = wave >> 1;          // 2 x 64 rows
  const int waveN = wave & 1;           // 2 x 128 cols

  v4f acc[4][8];
  #pragma unroll
  for (int i = 0; i < 4; ++i)
    #pragma unroll
    for (int j = 0; j < 8; ++j)
      acc[i][j] = (v4f){0.f, 0.f, 0.f, 0.f};

  // staging. A tile: 128 rows x 64 B = 512 chunks (2/thread); W: 256 rows = 1024
  // chunks (4/thread). slot s: r=s>>2, slot-col s&3, global col (s&3)^((r>>1)&3).
  const int sA0 = tid, sA1 = tid + 256;
  const int rA0 = sA0 >> 2, cA0 = (sA0 & 3) ^ ((rA0 >> 1) & 3);
  const int rA1 = sA1 >> 2, cA1 = (sA1 & 3) ^ ((rA1 >> 1) & 3);
  const char* gA0 = (const char*)xbf + (size_t)(mBase + rA0) * (Dn * 2) + cA0 * 16;
  const char* gA1 = (const char*)xbf + (size_t)(mBase + rA1) * (Dn * 2) + cA1 * 16;
  const int loA0 = sA0 * 16, loA1 = sA1 * 16;
  const char* gW[4]; int loW[4];
  #pragma unroll
  for (int p = 0; p < 4; ++p) {
    int s = tid + p * 256;
    int r = s >> 2, c = (s & 3) ^ ((r >> 1) & 3);
    gW[p] = (const char*)wbf + (size_t)(nBase + r) * (Dn * 2) + c * 16;
    loW[p] = s * 16;
  }

  // frag read offsets (swizzle-aware), relative to A / W region bases
  int aoffs[4], boffs[8];
  #pragma unroll
  for (int i = 0; i < 4; ++i) {
    int ra = waveM * 64 + i * 16 + l16;
    aoffs[i] = ra * 64 + ((quad ^ ((ra >> 1) & 3)) * 16);
  }
  #pragma unroll
  for (int j = 0; j < 8; ++j) {
    int rb = waveN * 128 + j * 16 + l16;
    boffs[j] = rb * 64 + ((quad ^ ((rb >> 1) & 3)) * 16);
  }

  // prologue: tiles 0,1 -> buffers 0,1 (12 loads in flight per thread)
  #pragma unroll
  for (int t = 0; t < 2; ++t) {
    char* Ab = lds + t * 24576;
    char* Wb = Ab + 8192;
    async16(gA0 + t * 64, Ab + loA0);
    async16(gA1 + t * 64, Ab + loA1);
    #pragma unroll
    for (int p = 0; p < 4; ++p) async16(gW[p] + t * 64, Wb + loW[p]);
  }

  #pragma unroll
  for (int kt = 0; kt < 16; ++kt) {
    const int cur = kt % 3;
    if (kt < 15) { WAIT_VM6(); } else { WAIT_VM0(); }  // tile kt's DMA landed (this wave)
    LGKM0_BAR();  // single barrier: tile kt ready everywhere + iter-(kt-1) reads drained
    char* Ab = lds + cur * 24576;
    char* Wb = Ab + 8192;
    if (kt + 2 < 16) {  // tile kt+2 -> buf read in iter kt-1 (just cleared)
      const int nx = (kt + 2) % 3;
      char* An = lds + nx * 24576;
      char* Wn = An + 8192;
      async16(gA0 + (kt + 2) * 64, An + loA0);
      async16(gA1 + (kt + 2) * 64, An + loA1);
      #pragma unroll
      for (int p = 0; p < 4; ++p) async16(gW[p] + (kt + 2) * 64, Wn + loW[p]);
    }
    v8bf af[4], bfv[8];
    #pragma unroll
    for (int i = 0; i < 4; ++i) af[i] = *(const v8bf*)(Ab + aoffs[i]);
    #pragma unroll
    for (int j = 0; j < 8; ++j) bfv[j] = *(const v8bf*)(Wb + boffs[j]);
    #pragma unroll
    for (int i = 0; i < 4; ++i)
      #pragma unroll
      for (int j = 0; j < 8; ++j)
        acc[i][j] = __builtin_amdgcn_mfma_f32_16x16x32_bf16(af[i], bfv[j], acc[i][j], 0, 0, 0);
  }

  // ---- epilogue: partial sums of e^{u}, u = 128*sims (e^{+64}-scaled) ----
  float ysqj[8], yrj[8], gj[8];
  #pragma unroll
  for (int j = 0; j < 8; ++j) {
    int col = nBase + waveN * 128 + j * 16 + l16;
    gj[j] = -2.f * fscale[col];
    ysqj[j] = ysqA[col];
    yrj[j] = yrA[col];
  }
  #pragma unroll
  for (int i = 0; i < 4; ++i) {
    #pragma unroll
    for (int r = 0; r < 4; ++r) {
      int row = mBase + waveM * 64 + i * 16 + quad * 4 + r;
      float xs = xsA[row];
      float xr2 = 2.f * xrA[row];
      float partial = 0.f;
      if (xs >= 0.99999f) {
        // clipped row: xr=1e5 -> z large -> u=64/z small.
        // sims~=1/(2z) (rel err 1/(4z^2)); e^u ~= 1+u+u^2/2 (err u^3/6).
        #pragma unroll
        for (int j = 0; j < 8; ++j) {
          float d = fmaxf(fmaf(gj[j], acc[i][j][r], xs + ysqj[j]), 0.f);
          float z = fmaf(d, xr2 * yrj[j], 1.f);
          float u = 64.f * __builtin_amdgcn_rcpf(z);
          partial += fmaf(u, fmaf(0.5f, u, 1.f), 1.f);
        }
      } else {
        // rare unclipped row: exact path
        #pragma unroll
        for (int j = 0; j < 8; ++j) {
          float d = fmaxf(fmaf(gj[j], acc[i][j][r], xs + ysqj[j]), 0.f);
          float z = fmaf(d, xr2 * yrj[j], 1.f);
          float sq = sqrtf(fmaf(z, z, -1.f));
          float u = 128.f * __builtin_amdgcn_rcpf(z + sq);
          partial += __expf(u);
        }
      }
      partial += __shfl_xor(partial, 1);
      partial += __shfl_xor(partial, 2);
      partial += __shfl_xor(partial, 4);
      partial += __shfl_xor(partial, 8);
      if (l16 == 0) partials[(size_t)row * 128 + nt * 2 + waveN] = partial;
    }
  }
}

// ---------------- final: label fix + row term + grid mean (atomic) ----------------
// partials are e^{+64}-scaled: S = sum_j e^{u_j}. term = -64 + log(S - e^{u_lab}
// + e^{64(phi+1)}) - 64*phi.
__global__ __launch_bounds__(256) void final_kernel(
    const float* __restrict__ x, const float* __restrict__ w,
    const int* __restrict__ labels, const float* __restrict__ fscale,
    const float* __restrict__ ysqA, const float* __restrict__ yrA,
    const float* __restrict__ xsA, const float* __restrict__ xrA,
    const float* __restrict__ partials, float* __restrict__ out)
{
  int row = blockIdx.x * 4 + (threadIdx.x >> 6);  // wave per row
  int lane = threadIdx.x & 63;
  const float* pr = partials + (size_t)row * 128;
  float sum = pr[lane] + pr[lane + 64];

  int lab = labels[row];
  const float4* xv = (const float4*)(x + (size_t)row * Dn);
  const float4* wv = (const float4*)(w + (size_t)lab * Dn);
  float4 a0 = xv[lane * 2], a1 = xv[lane * 2 + 1];
  float4 b0 = wv[lane * 2], b1 = wv[lane * 2 + 1];
  float dot = a0.x * b0.x + a0.y * b0.y + a0.z * b0.z + a0.w * b0.w
            + a1.x * b1.x + a1.y * b1.y + a1.z * b1.z + a1.w * b1.w;
  #pragma unroll
  for (int d = 1; d < 64; d <<= 1) {
    sum += __shfl_xor(sum, d);
    dot += __shfl_xor(dot, d);
  }

  __shared__ float red[4];
  if (lane == 0) {
    float xy = fscale[lab] * dot;  // fp32 exact label logit
    float diff = fmaxf(xsA[row] + ysqA[lab] - 2.f * xy, 0.f);
    float z = fmaf(2.f * diff, xrA[row] * yrA[lab], 1.f);
    float sq = sqrtf(fmaf(z, z, -1.f));
    float sims = 1.f / (z + sq);
    float u_lab = 128.f * sims;
    float cosv = fmaf(2.f, sims, -1.f);
    float sine = sqrtf(fmaxf(fmaf(-cosv, cosv, 1.f), 1e-7f));
    float phi = (cosv > -0.8775825619f)
                    ? (cosv * 0.8775825619f - sine * 0.4794255386f)
                    : (cosv - 0.2397127693f);
    float e_lab = __expf(u_lab);                          // e^{+64}-scaled cos term
    float e_phi = __expf(fminf(64.f * phi + 64.f, 80.f)); // scaled margin term
    red[threadIdx.x >> 6] = logf(sum - e_lab + e_phi) - 64.f * phi - 64.f;
  }
  __syncthreads();
  if (threadIdx.x == 0)
    atomicAdd(out, (red[0] + red[1] + red[2] + red[3]) * (1.f / (float)Bn));
}

extern "C" void kernel_launch(void* const* d_in, const int* in_sizes, int n_in,
                              void* d_out, int out_size, void* d_ws, size_t ws_size,
                              hipStream_t stream) {
  (void)in_sizes; (void)n_in; (void)out_size; (void)ws_size;
  const float* emb = (const float*)d_in[0];
  const int* labels = (const int*)d_in[1];
  const float* weight = (const float*)d_in[2];
  float* out = (float*)d_out;

  char* p = (char*)d_ws;
  __hip_bfloat16* wbf = (__hip_bfloat16*)p; p += (size_t)Cn * Dn * 2;  // 16 MB
  __hip_bfloat16* xbf = (__hip_bfloat16*)p; p += (size_t)Bn * Dn * 2;  // 2 MB
  float* fscale = (float*)p; p += (size_t)Cn * 4;
  float* ysqA  = (float*)p; p += (size_t)Cn * 4;
  float* yrA   = (float*)p; p += (size_t)Cn * 4;
  float* xsA   = (float*)p; p += (size_t)Bn * 4;
  float* xrA   = (float*)p; p += (size_t)Bn * 4;
  float* partials = (float*)p; p += (size_t)Bn * 128 * 4;  // 1 MB, written-once

  hipMemsetAsync(out, 0, sizeof(float), stream);  // atomicAdd target
  prep_kernel<<<(Cn + Bn) / 4, 256, 0, stream>>>(weight, emb, wbf, xbf, fscale, ysqA, yrA, xsA, xrA);
  gemm_kernel<<<(Bn / 128) * (Cn / 256), 256, 0, stream>>>(
      xbf, wbf, fscale, ysqA, yrA, xsA, xrA, partials);
  final_kernel<<<Bn / 4, 256, 0, stream>>>(emb, weight, labels, fscale, ysqA, yrA, xsA, xrA, partials, out);
}

// Round 10
// 130.028 us; speedup vs baseline: 1.0670x; 1.0512x over previous
//
#include <hip/hip_runtime.h>
#include <hip/hip_bf16.h>
#include <math.h>

#define Bn 2048
#define Dn 512
#define Cn 16384

typedef float v4f __attribute__((ext_vector_type(4)));

#define WAIT_VM4()  asm volatile("s_waitcnt vmcnt(4)" ::: "memory")
#define WAIT_VM0()  asm volatile("s_waitcnt vmcnt(0)" ::: "memory")
#define LGKM0_BAR() asm volatile("s_waitcnt lgkmcnt(0)\n\ts_barrier" ::: "memory")

__device__ __forceinline__ void async16(const void* g, void* l) {
  __builtin_amdgcn_global_load_lds(
      (const __attribute__((address_space(1))) char*)g,
      (__attribute__((address_space(3))) char*)l, 16, 0, 0);
}

// ---------------- prep: wave-per-row norms, scales, fp8 e4m3 conversion ----------------
// Inputs pre-scaled by 16 into e4m3's normal range (|16w|<=1.8, |16x|~<5, max 448).
// MFMA then computes 256*(x.w); epilogue folds the 1/256 into gj.
__global__ __launch_bounds__(256) void prep_kernel(
    const float* __restrict__ w, const float* __restrict__ x,
    char* __restrict__ wq8, char* __restrict__ xq8,
    float* __restrict__ fscale, float* __restrict__ ysqA, float* __restrict__ yrA,
    float* __restrict__ xsA, float* __restrict__ xrA)
{
  int gw = (blockIdx.x * 256 + threadIdx.x) >> 6;  // wave id == row
  int lane = threadIdx.x & 63;
  bool isW = gw < Cn;
  const float* src = isW ? (w + (size_t)gw * Dn) : (x + (size_t)(gw - Cn) * Dn);
  const float4* s4 = (const float4*)src;
  float4 a = s4[lane * 2], b = s4[lane * 2 + 1];  // 32 B/lane, coalesced
  float ss = a.x * a.x + a.y * a.y + a.z * a.z + a.w * a.w
           + b.x * b.x + b.y * b.y + b.z * b.z + b.w * b.w;
  #pragma unroll
  for (int d = 1; d < 64; d <<= 1) ss += __shfl_xor(ss, d);

  // pack 8 floats -> 8 fp8 e4m3 bytes (OCP, gfx950 HW cvt)
  int w0 = __builtin_amdgcn_cvt_pk_fp8_f32(a.x * 16.f, a.y * 16.f, 0, false);
  w0     = __builtin_amdgcn_cvt_pk_fp8_f32(a.z * 16.f, a.w * 16.f, w0, true);
  int w1 = __builtin_amdgcn_cvt_pk_fp8_f32(b.x * 16.f, b.y * 16.f, 0, false);
  w1     = __builtin_amdgcn_cvt_pk_fp8_f32(b.z * 16.f, b.w * 16.f, w1, true);
  char* dst = isW ? (wq8 + (size_t)gw * Dn) : (xq8 + (size_t)(gw - Cn) * Dn);
  ((int2*)dst)[lane] = make_int2(w0, w1);  // 8 B/lane, coalesced

  if (lane == 0) {
    if (isW) {
      float n = fmaxf(sqrtf(ss), 1e-7f);
      float t = tanhf(n);           // c=1: tanh(sqrt_c * norm)
      float tc = fminf(t, 0.95f);   // radius clip folded into scale
      fscale[gw] = tc / n;          // proto = fscale * w
      float ys = tc * tc;           // ||proto||^2
      ysqA[gw] = ys;
      yrA[gw] = 1.f / (1.f - fminf(ys, 1.f - 1e-5f));
    } else {
      int r = gw - Cn;
      xsA[r] = ss;
      xrA[r] = 1.f / (1.f - fminf(ss, 1.f - 1e-5f));
    }
  }
}

// ------- fp8 MFMA GEMM: 128x128 block, 64x64 wave tiles, 3 waves/SIMD -------
// R10: dtype fp8 e4m3 + occupancy attack. acc 4x4 (64 AGPR) + ~80 VGPR ~= 145
// -> 3 waves/SIMD (vs 252 regs / 2 waves before); LDS 3 x 16 KB = 48 KB -> 3
// blocks/CU. BK=64 (8 iters, 2 k-steps of the 16x16x32 fp8 MFMA per iter).
// Keeps R9's single-barrier triple-buffer pipeline: WAIT_VM4 -> lgkm0+barrier
// -> prefetch kt+2 -> ds_read -> MFMA. Ledger: prologue 8 loads (tiles 0,1);
// vmcnt(4) at iter top drains exactly tile kt; 4 async16/thread/iter.
// Frags are 8 B/lane (ds_read_b64); chunk swizzle c^((r>>1)&3) makes each b64
// hit all 32 banks exactly 4x (uniform) = conflict-free.
__global__ __launch_bounds__(256, 3) void gemm_kernel(
    const char* __restrict__ xq8, const char* __restrict__ wq8,
    const float* __restrict__ fscale, const float* __restrict__ ysqA,
    const float* __restrict__ yrA, const float* __restrict__ xsA,
    const float* __restrict__ xrA, float* __restrict__ partials)
{
  __shared__ int4 ldsv[3072];  // 48 KB: buf{0,1,2} x [A 8K][W 8K]
  char* lds = (char*)ldsv;

  const int bid = blockIdx.x;           // 2048 blocks
  const int xcd = bid & 7;              // round-robin dispatch across XCDs
  const int loc = bid >> 3;             // 0..255
  const int mt  = loc & 15;             // 16 m-tiles of 128 (m fastest: share W band)
  const int nt  = (xcd << 4) | (loc >> 4);  // 128 n-tiles of 128, banded per XCD
  const int mBase = mt * 128;
  const int nBase = nt * 128;
  const int tid = threadIdx.x;
  const int lane = tid & 63;
  const int wave = tid >> 6;
  const int quad = lane >> 4;
  const int l16 = lane & 15;
  const int waveM = wave >> 1;          // 2 x 64 rows
  const int waveN = wave & 1;           // 2 x 64 cols

  v4f acc[4][4];
  #pragma unroll
  for (int i = 0; i < 4; ++i)
    #pragma unroll
    for (int j = 0; j < 4; ++j)
      acc[i][j] = (v4f){0.f, 0.f, 0.f, 0.f};

  // staging: A tile 128 rows x 64 B (fp8, BK=64) = 512 chunks of 16 B (2/thread);
  // W same. slot s: r=s>>2, slot-col s&3, global chunk col (s&3)^((r>>1)&3).
  const int s0 = tid, s1 = tid + 256;
  const int r0 = s0 >> 2, c0 = (s0 & 3) ^ ((r0 >> 1) & 3);
  const int r1 = s1 >> 2, c1 = (s1 & 3) ^ ((r1 >> 1) & 3);
  const char* gA0 = xq8 + (size_t)(mBase + r0) * Dn + c0 * 16;
  const char* gA1 = xq8 + (size_t)(mBase + r1) * Dn + c1 * 16;
  const char* gW0 = wq8 + (size_t)(nBase + r0) * Dn + c0 * 16;
  const char* gW1 = wq8 + (size_t)(nBase + r1) * Dn + c1 * 16;
  const int lo0 = s0 * 16, lo1 = s1 * 16;

  // frag b64 offsets: row ra, k-step s, quad q ->
  //   ra*64 + ((2s + (q>>1)) ^ ((ra>>1)&3))*16 + (q&1)*8
  // ((ra>>1)&3) == ((l16>>1)&3) for ra = waveX*64 + i*16 + l16 (i*8 = 0 mod 4).
  const int kx = (l16 >> 1) & 3;
  int aoff[2], boff[2];
  #pragma unroll
  for (int s = 0; s < 2; ++s) {
    int chunk = (2 * s + (quad >> 1)) ^ kx;
    aoff[s] = (waveM * 64 + l16) * 64 + chunk * 16 + (quad & 1) * 8;
    boff[s] = (waveN * 64 + l16) * 64 + chunk * 16 + (quad & 1) * 8;
  }

  // prologue: tiles 0,1 -> buffers 0,1 (8 loads in flight per thread)
  #pragma unroll
  for (int t = 0; t < 2; ++t) {
    char* Ab = lds + t * 16384;
    char* Wb = Ab + 8192;
    async16(gA0 + t * 64, Ab + lo0);
    async16(gA1 + t * 64, Ab + lo1);
    async16(gW0 + t * 64, Wb + lo0);
    async16(gW1 + t * 64, Wb + lo1);
  }

  #pragma unroll
  for (int kt = 0; kt < 8; ++kt) {
    const int cur = kt % 3;
    if (kt < 7) { WAIT_VM4(); } else { WAIT_VM0(); }  // tile kt's DMA landed (this wave)
    LGKM0_BAR();  // single barrier: tile kt ready everywhere + iter-(kt-1) reads drained
    char* Ab = lds + cur * 16384;
    char* Wb = Ab + 8192;
    if (kt + 2 < 8) {  // tile kt+2 -> buffer read in iter kt-1 (just cleared)
      const int nx = (kt + 2) % 3;
      char* An = lds + nx * 16384;
      char* Wn = An + 8192;
      async16(gA0 + (kt + 2) * 64, An + lo0);
      async16(gA1 + (kt + 2) * 64, An + lo1);
      async16(gW0 + (kt + 2) * 64, Wn + lo0);
      async16(gW1 + (kt + 2) * 64, Wn + lo1);
    }
    long af[4][2], bf[4][2];
    #pragma unroll
    for (int s = 0; s < 2; ++s) {
      #pragma unroll
      for (int i = 0; i < 4; ++i) af[i][s] = *(const long*)(Ab + aoff[s] + i * 1024);
      #pragma unroll
      for (int j = 0; j < 4; ++j) bf[j][s] = *(const long*)(Wb + boff[s] + j * 1024);
    }
    #pragma unroll
    for (int s = 0; s < 2; ++s)
      #pragma unroll
      for (int i = 0; i < 4; ++i)
        #pragma unroll
        for (int j = 0; j < 4; ++j)
          acc[i][j] = __builtin_amdgcn_mfma_f32_16x16x32_fp8_fp8(af[i][s], bf[j][s], acc[i][j], 0, 0, 0);
  }

  // ---- epilogue: partial sums of e^{u}, u = 128*sims (e^{+64}-scaled) ----
  // acc = 256*(x.w_raw) due to the 16x input prescale -> fold 1/256 into gj.
  float ysqj[4], yrj[4], gj[4];
  #pragma unroll
  for (int j = 0; j < 4; ++j) {
    int col = nBase + waveN * 64 + j * 16 + l16;
    gj[j] = -2.f * fscale[col] * (1.f / 256.f);
    ysqj[j] = ysqA[col];
    yrj[j] = yrA[col];
  }
  #pragma unroll
  for (int i = 0; i < 4; ++i) {
    #pragma unroll
    for (int r = 0; r < 4; ++r) {
      int row = mBase + waveM * 64 + i * 16 + quad * 4 + r;
      float xs = xsA[row];
      float xr2 = 2.f * xrA[row];
      float partial = 0.f;
      if (xs >= 0.99999f) {
        // clipped row: xr=1e5 -> z large -> u=64/z small.
        // sims~=1/(2z) (rel err 1/(4z^2)); e^u ~= 1+u+u^2/2 (err u^3/6).
        #pragma unroll
        for (int j = 0; j < 4; ++j) {
          float d = fmaxf(fmaf(gj[j], acc[i][j][r], xs + ysqj[j]), 0.f);
          float z = fmaf(d, xr2 * yrj[j], 1.f);
          float u = 64.f * __builtin_amdgcn_rcpf(z);
          partial += fmaf(u, fmaf(0.5f, u, 1.f), 1.f);
        }
      } else {
        // rare unclipped row: exact path
        #pragma unroll
        for (int j = 0; j < 4; ++j) {
          float d = fmaxf(fmaf(gj[j], acc[i][j][r], xs + ysqj[j]), 0.f);
          float z = fmaf(d, xr2 * yrj[j], 1.f);
          float sq = sqrtf(fmaf(z, z, -1.f));
          float u = 128.f * __builtin_amdgcn_rcpf(z + sq);
          partial += __expf(u);
        }
      }
      partial += __shfl_xor(partial, 1);
      partial += __shfl_xor(partial, 2);
      partial += __shfl_xor(partial, 4);
      partial += __shfl_xor(partial, 8);
      if (l16 == 0) partials[(size_t)row * 256 + nt * 2 + waveN] = partial;
    }
  }
}

// ---------------- final: label fix + row term + grid mean (atomic) ----------------
// partials are e^{+64}-scaled: S = sum_j e^{u_j}. term = -64 + log(S - e^{u_lab}
// + e^{64(phi+1)}) - 64*phi. Label path is exact fp32 (no fp8 error here).
__global__ __launch_bounds__(256) void final_kernel(
    const float* __restrict__ x, const float* __restrict__ w,
    const int* __restrict__ labels, const float* __restrict__ fscale,
    const float* __restrict__ ysqA, const float* __restrict__ yrA,
    const float* __restrict__ xsA, const float* __restrict__ xrA,
    const float* __restrict__ partials, float* __restrict__ out)
{
  int row = blockIdx.x * 4 + (threadIdx.x >> 6);  // wave per row
  int lane = threadIdx.x & 63;
  const float* pr = partials + (size_t)row * 256;
  float sum = pr[lane] + pr[lane + 64] + pr[lane + 128] + pr[lane + 192];

  int lab = labels[row];
  const float4* xv = (const float4*)(x + (size_t)row * Dn);
  const float4* wv = (const float4*)(w + (size_t)lab * Dn);
  float4 a0 = xv[lane * 2], a1 = xv[lane * 2 + 1];
  float4 b0 = wv[lane * 2], b1 = wv[lane * 2 + 1];
  float dot = a0.x * b0.x + a0.y * b0.y + a0.z * b0.z + a0.w * b0.w
            + a1.x * b1.x + a1.y * b1.y + a1.z * b1.z + a1.w * b1.w;
  #pragma unroll
  for (int d = 1; d < 64; d <<= 1) {
    sum += __shfl_xor(sum, d);
    dot += __shfl_xor(dot, d);
  }

  __shared__ float red[4];
  if (lane == 0) {
    float xy = fscale[lab] * dot;  // fp32 exact label logit
    float diff = fmaxf(xsA[row] + ysqA[lab] - 2.f * xy, 0.f);
    float z = fmaf(2.f * diff, xrA[row] * yrA[lab], 1.f);
    float sq = sqrtf(fmaf(z, z, -1.f));
    float sims = 1.f / (z + sq);
    float u_lab = 128.f * sims;
    float cosv = fmaf(2.f, sims, -1.f);
    float sine = sqrtf(fmaxf(fmaf(-cosv, cosv, 1.f), 1e-7f));
    float phi = (cosv > -0.8775825619f)
                    ? (cosv * 0.8775825619f - sine * 0.4794255386f)
                    : (cosv - 0.2397127693f);
    float e_lab = __expf(u_lab);                          // e^{+64}-scaled cos term
    float e_phi = __expf(fminf(64.f * phi + 64.f, 80.f)); // scaled margin term
    red[threadIdx.x >> 6] = logf(sum - e_lab + e_phi) - 64.f * phi - 64.f;
  }
  __syncthreads();
  if (threadIdx.x == 0)
    atomicAdd(out, (red[0] + red[1] + red[2] + red[3]) * (1.f / (float)Bn));
}

extern "C" void kernel_launch(void* const* d_in, const int* in_sizes, int n_in,
                              void* d_out, int out_size, void* d_ws, size_t ws_size,
                              hipStream_t stream) {
  (void)in_sizes; (void)n_in; (void)out_size; (void)ws_size;
  const float* emb = (const float*)d_in[0];
  const int* labels = (const int*)d_in[1];
  const float* weight = (const float*)d_in[2];
  float* out = (float*)d_out;

  char* p = (char*)d_ws;
  char* wq8 = p; p += (size_t)Cn * Dn;       // 8 MB fp8
  char* xq8 = p; p += (size_t)Bn * Dn;       // 1 MB fp8
  float* fscale = (float*)p; p += (size_t)Cn * 4;
  float* ysqA  = (float*)p; p += (size_t)Cn * 4;
  float* yrA   = (float*)p; p += (size_t)Cn * 4;
  float* xsA   = (float*)p; p += (size_t)Bn * 4;
  float* xrA   = (float*)p; p += (size_t)Bn * 4;
  float* partials = (float*)p; p += (size_t)Bn * 256 * 4;  // 2 MB, written-once

  hipMemsetAsync(out, 0, sizeof(float), stream);  // atomicAdd target
  prep_kernel<<<(Cn + Bn) / 4, 256, 0, stream>>>(weight, emb, wq8, xq8, fscale, ysqA, yrA, xsA, xrA);
  gemm_kernel<<<(Bn / 128) * (Cn / 128), 256, 0, stream>>>(
      xq8, wq8, fscale, ysqA, yrA, xsA, xrA, partials);
  final_kernel<<<Bn / 4, 256, 0, stream>>>(emb, weight, labels, fscale, ysqA, yrA, xsA, xrA, partials, out);
}

// Round 12
// 126.614 us; speedup vs baseline: 1.0958x; 1.0270x over previous
//
#include <hip/hip_runtime.h>
#include <hip/hip_cooperative_groups.h>
#include <math.h>

namespace cg = cooperative_groups;

#define Bn 2048
#define Dn 512
#define Cn 16384

typedef float v4f __attribute__((ext_vector_type(4)));

#define WAIT_VM4()  asm volatile("s_waitcnt vmcnt(4)" ::: "memory")
#define WAIT_VM0()  asm volatile("s_waitcnt vmcnt(0)" ::: "memory")
#define RAW_BAR()   asm volatile("s_barrier" ::: "memory")
#define LGKM0_BAR() asm volatile("s_waitcnt lgkmcnt(0)\n\ts_barrier" ::: "memory")

__device__ __forceinline__ void async16(const void* g, void* l) {
  __builtin_amdgcn_global_load_lds(
      (const __attribute__((address_space(1))) char*)g,
      (__attribute__((address_space(3))) char*)l, 16, 0, 0);
}

// ================= shared device pieces (used by both paths) =================

// wave-per-row: norm, scales, fp8 e4m3 conversion (16x prescale into normal range)
__device__ __forceinline__ void prep_row(
    int row, int lane, const float* __restrict__ w, const float* __restrict__ x,
    char* __restrict__ wq8, char* __restrict__ xq8,
    float* __restrict__ fscale, float* __restrict__ ysqA, float* __restrict__ yrA,
    float* __restrict__ xsA, float* __restrict__ xrA)
{
  bool isW = row < Cn;
  const float* src = isW ? (w + (size_t)row * Dn) : (x + (size_t)(row - Cn) * Dn);
  const float4* s4 = (const float4*)src;
  float4 a = s4[lane * 2], b = s4[lane * 2 + 1];
  float ss = a.x * a.x + a.y * a.y + a.z * a.z + a.w * a.w
           + b.x * b.x + b.y * b.y + b.z * b.z + b.w * b.w;
  #pragma unroll
  for (int d = 1; d < 64; d <<= 1) ss += __shfl_xor(ss, d);

  int w0 = __builtin_amdgcn_cvt_pk_fp8_f32(a.x * 16.f, a.y * 16.f, 0, false);
  w0     = __builtin_amdgcn_cvt_pk_fp8_f32(a.z * 16.f, a.w * 16.f, w0, true);
  int w1 = __builtin_amdgcn_cvt_pk_fp8_f32(b.x * 16.f, b.y * 16.f, 0, false);
  w1     = __builtin_amdgcn_cvt_pk_fp8_f32(b.z * 16.f, b.w * 16.f, w1, true);
  char* dst = isW ? (wq8 + (size_t)row * Dn) : (xq8 + (size_t)(row - Cn) * Dn);
  ((int2*)dst)[lane] = make_int2(w0, w1);

  if (lane == 0) {
    if (isW) {
      float n = fmaxf(sqrtf(ss), 1e-7f);
      float t = tanhf(n);           // c=1: tanh(sqrt_c * norm)
      float tc = fminf(t, 0.95f);   // radius clip folded into scale
      fscale[row] = tc / n;
      float ys = tc * tc;
      ysqA[row] = ys;
      yrA[row] = 1.f / (1.f - fminf(ys, 1.f - 1e-5f));
    } else {
      int r = row - Cn;
      xsA[r] = ss;
      xrA[r] = 1.f / (1.f - fminf(ss, 1.f - 1e-5f));
    }
  }
}

// one 128x128 fp8 GEMM job: 2-buffer (32 KB) vmcnt pipeline, R8-proven ordering
__device__ __forceinline__ void gemm_job(
    int job, int tid, char* lds,
    const char* __restrict__ xq8, const char* __restrict__ wq8,
    const float* __restrict__ fscale, const float* __restrict__ ysqA,
    const float* __restrict__ yrA, const float* __restrict__ xsA,
    const float* __restrict__ xrA, float* __restrict__ partials)
{
  const int xcd = job & 7;
  const int loc = job >> 3;
  const int mt  = loc & 15;
  const int nt  = (xcd << 4) | (loc >> 4);
  const int mBase = mt * 128;
  const int nBase = nt * 128;
  const int lane = tid & 63;
  const int wv = tid >> 6;
  const int quad = lane >> 4;
  const int l16 = lane & 15;
  const int waveM = wv >> 1;
  const int waveN = wv & 1;

  v4f acc[4][4];
  #pragma unroll
  for (int i = 0; i < 4; ++i)
    #pragma unroll
    for (int j = 0; j < 4; ++j)
      acc[i][j] = (v4f){0.f, 0.f, 0.f, 0.f};

  // staging: slot s -> r=s>>2, global chunk col (s&3)^((r>>1)&3)  (conflict-free)
  const int s0 = tid, s1 = tid + 256;
  const int r0 = s0 >> 2, c0 = (s0 & 3) ^ ((r0 >> 1) & 3);
  const int r1 = s1 >> 2, c1 = (s1 & 3) ^ ((r1 >> 1) & 3);
  const char* gA0 = xq8 + (size_t)(mBase + r0) * Dn + c0 * 16;
  const char* gA1 = xq8 + (size_t)(mBase + r1) * Dn + c1 * 16;
  const char* gW0 = wq8 + (size_t)(nBase + r0) * Dn + c0 * 16;
  const char* gW1 = wq8 + (size_t)(nBase + r1) * Dn + c1 * 16;
  const int lo0 = s0 * 16, lo1 = s1 * 16;

  const int kx = (l16 >> 1) & 3;
  int aoff[2], boff[2];
  #pragma unroll
  for (int s = 0; s < 2; ++s) {
    int chunk = (2 * s + (quad >> 1)) ^ kx;
    aoff[s] = (waveM * 64 + l16) * 64 + chunk * 16 + (quad & 1) * 8;
    boff[s] = (waveN * 64 + l16) * 64 + chunk * 16 + (quad & 1) * 8;
  }

  // prologue: tiles 0,1 -> buffers 0,1 (8 loads in flight)
  #pragma unroll
  for (int t = 0; t < 2; ++t) {
    char* Ab = lds + t * 16384;
    char* Wb = Ab + 8192;
    async16(gA0 + t * 64, Ab + lo0);
    async16(gA1 + t * 64, Ab + lo1);
    async16(gW0 + t * 64, Wb + lo0);
    async16(gW1 + t * 64, Wb + lo1);
  }

  #pragma unroll
  for (int kt = 0; kt < 8; ++kt) {
    const int cur = kt & 1;
    if (kt < 7) { WAIT_VM4(); } else { WAIT_VM0(); }  // tile kt landed (this wave)
    RAW_BAR();                                         // ...for all waves
    char* Ab = lds + cur * 16384;
    char* Wb = Ab + 8192;
    long af[4][2], bf[4][2];
    #pragma unroll
    for (int s = 0; s < 2; ++s) {
      #pragma unroll
      for (int i = 0; i < 4; ++i) af[i][s] = *(const long*)(Ab + aoff[s] + i * 1024);
      #pragma unroll
      for (int j = 0; j < 4; ++j) bf[j][s] = *(const long*)(Wb + boff[s] + j * 1024);
    }
    #pragma unroll
    for (int s = 0; s < 2; ++s)
      #pragma unroll
      for (int i = 0; i < 4; ++i)
        #pragma unroll
        for (int j = 0; j < 4; ++j)
          acc[i][j] = __builtin_amdgcn_mfma_f32_16x16x32_fp8_fp8(af[i][s], bf[j][s], acc[i][j], 0, 0, 0);
    LGKM0_BAR();  // all waves' reads of buf[cur] drained -> safe to rewrite
    if (kt + 2 < 8) {  // tile kt+2 into buf[cur]
      async16(gA0 + (kt + 2) * 64, Ab + lo0);
      async16(gA1 + (kt + 2) * 64, Ab + lo1);
      async16(gW0 + (kt + 2) * 64, Wb + lo0);
      async16(gW1 + (kt + 2) * 64, Wb + lo1);
    }
  }

  // epilogue: e^{+64}-scaled partial sums; 1/256 folds the 16x prescale
  float ysqj[4], yrj[4], gj[4];
  #pragma unroll
  for (int j = 0; j < 4; ++j) {
    int col = nBase + waveN * 64 + j * 16 + l16;
    gj[j] = -2.f * fscale[col] * (1.f / 256.f);
    ysqj[j] = ysqA[col];
    yrj[j] = yrA[col];
  }
  #pragma unroll
  for (int i = 0; i < 4; ++i) {
    #pragma unroll
    for (int r = 0; r < 4; ++r) {
      int row = mBase + waveM * 64 + i * 16 + quad * 4 + r;
      float xs = xsA[row];
      float xr2 = 2.f * xrA[row];
      float partial = 0.f;
      if (xs >= 0.99999f) {
        // clipped row: z large -> sims~=1/(2z), e^u ~= 1+u+u^2/2
        #pragma unroll
        for (int j = 0; j < 4; ++j) {
          float d = fmaxf(fmaf(gj[j], acc[i][j][r], xs + ysqj[j]), 0.f);
          float z = fmaf(d, xr2 * yrj[j], 1.f);
          float u = 64.f * __builtin_amdgcn_rcpf(z);
          partial += fmaf(u, fmaf(0.5f, u, 1.f), 1.f);
        }
      } else {
        #pragma unroll
        for (int j = 0; j < 4; ++j) {
          float d = fmaxf(fmaf(gj[j], acc[i][j][r], xs + ysqj[j]), 0.f);
          float z = fmaf(d, xr2 * yrj[j], 1.f);
          float sq = sqrtf(fmaf(z, z, -1.f));
          float u = 128.f * __builtin_amdgcn_rcpf(z + sq);
          partial += __expf(u);
        }
      }
      partial += __shfl_xor(partial, 1);
      partial += __shfl_xor(partial, 2);
      partial += __shfl_xor(partial, 4);
      partial += __shfl_xor(partial, 8);
      if (l16 == 0) partials[(size_t)row * 256 + nt * 2 + waveN] = partial;
    }
  }
}

// wave-per-row: exact fp32 label fix; returns the row term (valid on lane 0)
__device__ __forceinline__ float final_row_term(
    int row, int lane,
    const float* __restrict__ x, const float* __restrict__ w,
    const int* __restrict__ labels, const float* __restrict__ fscale,
    const float* __restrict__ ysqA, const float* __restrict__ yrA,
    const float* __restrict__ xsA, const float* __restrict__ xrA,
    const float* __restrict__ partials)
{
  const float* pr = partials + (size_t)row * 256;
  float sum = pr[lane] + pr[lane + 64] + pr[lane + 128] + pr[lane + 192];

  int lab = labels[row];
  const float4* xv = (const float4*)(x + (size_t)row * Dn);
  const float4* wv4 = (const float4*)(w + (size_t)lab * Dn);
  float4 a0 = xv[lane * 2], a1 = xv[lane * 2 + 1];
  float4 b0 = wv4[lane * 2], b1 = wv4[lane * 2 + 1];
  float dot = a0.x * b0.x + a0.y * b0.y + a0.z * b0.z + a0.w * b0.w
            + a1.x * b1.x + a1.y * b1.y + a1.z * b1.z + a1.w * b1.w;
  #pragma unroll
  for (int d = 1; d < 64; d <<= 1) {
    sum += __shfl_xor(sum, d);
    dot += __shfl_xor(dot, d);
  }

  float term = 0.f;
  if (lane == 0) {
    float xy = fscale[lab] * dot;
    float diff = fmaxf(xsA[row] + ysqA[lab] - 2.f * xy, 0.f);
    float z = fmaf(2.f * diff, xrA[row] * yrA[lab], 1.f);
    float sq = sqrtf(fmaf(z, z, -1.f));
    float sims = 1.f / (z + sq);
    float u_lab = 128.f * sims;
    float cosv = fmaf(2.f, sims, -1.f);
    float sine = sqrtf(fmaxf(fmaf(-cosv, cosv, 1.f), 1e-7f));
    float phi = (cosv > -0.8775825619f)
                    ? (cosv * 0.8775825619f - sine * 0.4794255386f)
                    : (cosv - 0.2397127693f);
    float e_lab = __expf(u_lab);
    float e_phi = __expf(fminf(64.f * phi + 64.f, 80.f));
    term = logf(sum - e_lab + e_phi) - 64.f * phi - 64.f;
  }
  return term;
}

// ================= path A: one cooperative dispatch =================
// 512 blocks x 256 thr, 32 KB LDS -> >=2 blocks/CU under ANY occupancy table
// (even the conservative 64 KB one that likely rejected R11's 48 KB launch).
__global__ __launch_bounds__(256, 2) void fused_kernel(
    const float* __restrict__ w, const float* __restrict__ x,
    const int* __restrict__ labels,
    char* __restrict__ wq8, char* __restrict__ xq8,
    float* __restrict__ fscale, float* __restrict__ ysqA, float* __restrict__ yrA,
    float* __restrict__ xsA, float* __restrict__ xrA,
    float* __restrict__ partials, float* __restrict__ terms, float* __restrict__ out)
{
  __shared__ int4 ldsv[2048];  // 32 KB: buf{0,1} x [A 8K][W 8K]
  char* lds = (char*)ldsv;
  cg::grid_group grid = cg::this_grid();
  const int tid = threadIdx.x, lane = tid & 63, wv = tid >> 6;

  // phase 1: prep (2048 waves x 9 rows)
  for (int row = (blockIdx.x << 2) | wv; row < Cn + Bn; row += 2048)
    prep_row(row, lane, w, x, wq8, xq8, fscale, ysqA, yrA, xsA, xrA);
  grid.sync();

  // phase 2: 4 gemm jobs per block (job&7 == bid&7: XCD banding preserved)
  #pragma unroll 1
  for (int t = 0; t < 4; ++t)
    gemm_job(blockIdx.x + t * 512, tid, lds, xq8, wq8, fscale, ysqA, yrA, xsA, xrA, partials);
  grid.sync();

  // phase 3: label fix, one term per block
  {
    int row = blockIdx.x * 4 + wv;
    float term = final_row_term(row, lane, x, w, labels, fscale, ysqA, yrA, xsA, xrA, partials);
    float* red = (float*)lds;  // gemm LDS dead (all DMA drained, reads done)
    if (lane == 0) red[wv] = term;
    __syncthreads();
    if (tid == 0) terms[blockIdx.x] = red[0] + red[1] + red[2] + red[3];
  }
  grid.sync();

  // phase 4: block 0 reduces 512 terms
  if (blockIdx.x == 0) {
    float a = terms[tid] + terms[tid + 256];
    #pragma unroll
    for (int d = 1; d < 64; d <<= 1) a += __shfl_xor(a, d);
    float* red = (float*)lds;
    if (lane == 0) red[wv] = a;
    __syncthreads();
    if (tid == 0) out[0] = (red[0] + red[1] + red[2] + red[3]) * (1.f / (float)Bn);
  }
}

// ================= path B: proven 4-dispatch fallback =================
__global__ __launch_bounds__(256) void prep_kernel(
    const float* __restrict__ w, const float* __restrict__ x,
    char* __restrict__ wq8, char* __restrict__ xq8,
    float* __restrict__ fscale, float* __restrict__ ysqA, float* __restrict__ yrA,
    float* __restrict__ xsA, float* __restrict__ xrA)
{
  int row = (blockIdx.x * 256 + threadIdx.x) >> 6;
  prep_row(row, threadIdx.x & 63, w, x, wq8, xq8, fscale, ysqA, yrA, xsA, xrA);
}

__global__ __launch_bounds__(256, 3) void gemm_kernel(
    const char* __restrict__ xq8, const char* __restrict__ wq8,
    const float* __restrict__ fscale, const float* __restrict__ ysqA,
    const float* __restrict__ yrA, const float* __restrict__ xsA,
    const float* __restrict__ xrA, float* __restrict__ partials)
{
  __shared__ int4 ldsv[2048];  // 32 KB
  gemm_job(blockIdx.x, threadIdx.x, (char*)ldsv, xq8, wq8, fscale, ysqA, yrA, xsA, xrA, partials);
}

__global__ __launch_bounds__(256) void final_kernel(
    const float* __restrict__ x, const float* __restrict__ w,
    const int* __restrict__ labels, const float* __restrict__ fscale,
    const float* __restrict__ ysqA, const float* __restrict__ yrA,
    const float* __restrict__ xsA, const float* __restrict__ xrA,
    const float* __restrict__ partials, float* __restrict__ out)
{
  int row = blockIdx.x * 4 + (threadIdx.x >> 6);
  float term = final_row_term(row, threadIdx.x & 63, x, w, labels, fscale,
                              ysqA, yrA, xsA, xrA, partials);
  __shared__ float red[4];
  if ((threadIdx.x & 63) == 0) red[threadIdx.x >> 6] = term;
  __syncthreads();
  if (threadIdx.x == 0)
    atomicAdd(out, (red[0] + red[1] + red[2] + red[3]) * (1.f / (float)Bn));
}

extern "C" void kernel_launch(void* const* d_in, const int* in_sizes, int n_in,
                              void* d_out, int out_size, void* d_ws, size_t ws_size,
                              hipStream_t stream) {
  (void)in_sizes; (void)n_in; (void)out_size; (void)ws_size;
  const float* emb = (const float*)d_in[0];
  const int* labels = (const int*)d_in[1];
  const float* weight = (const float*)d_in[2];
  float* out = (float*)d_out;

  char* p = (char*)d_ws;
  char* wq8 = p; p += (size_t)Cn * Dn;       // 8 MB fp8
  char* xq8 = p; p += (size_t)Bn * Dn;       // 1 MB fp8
  float* fscale = (float*)p; p += (size_t)Cn * 4;
  float* ysqA  = (float*)p; p += (size_t)Cn * 4;
  float* yrA   = (float*)p; p += (size_t)Cn * 4;
  float* xsA   = (float*)p; p += (size_t)Bn * 4;
  float* xrA   = (float*)p; p += (size_t)Bn * 4;
  float* partials = (float*)p; p += (size_t)Bn * 256 * 4;  // 2 MB, written-once
  float* terms = (float*)p; p += 512 * 4;                  // written-once

  // deterministic guard: cooperative support + >=2 co-resident blocks/CU
  int dev = 0;
  hipGetDevice(&dev);
  int coopAttr = 0;
  hipDeviceGetAttribute(&coopAttr, hipDeviceAttributeCooperativeLaunch, dev);
  int maxPerCU = 0;
  hipOccupancyMaxActiveBlocksPerMultiprocessor(&maxPerCU, (const void*)fused_kernel, 256, 0);

  hipError_t le = hipErrorUnknown;
  if (coopAttr == 1 && maxPerCU >= 2) {
    void* args[] = {(void*)&weight, (void*)&emb, (void*)&labels,
                    (void*)&wq8, (void*)&xq8, (void*)&fscale, (void*)&ysqA,
                    (void*)&yrA, (void*)&xsA, (void*)&xrA,
                    (void*)&partials, (void*)&terms, (void*)&out};
    le = hipLaunchCooperativeKernel((const void*)fused_kernel, dim3(512), dim3(256),
                                    args, 0, stream);
  }
  if (le != hipSuccess) {
    // proven multi-dispatch path (R10 structure)
    hipMemsetAsync(out, 0, sizeof(float), stream);
    prep_kernel<<<(Cn + Bn) / 4, 256, 0, stream>>>(weight, emb, wq8, xq8, fscale, ysqA, yrA, xsA, xrA);
    gemm_kernel<<<(Bn / 128) * (Cn / 128), 256, 0, stream>>>(
        xq8, wq8, fscale, ysqA, yrA, xsA, xrA, partials);
    final_kernel<<<Bn / 4, 256, 0, stream>>>(emb, weight, labels, fscale, ysqA, yrA, xsA, xrA, partials, out);
  }
}

// Round 13
// 126.280 us; speedup vs baseline: 1.0986x; 1.0026x over previous
//
#include <hip/hip_runtime.h>
#include <hip/hip_cooperative_groups.h>
#include <math.h>

namespace cg = cooperative_groups;

#define Bn 2048
#define Dn 512
#define Cn 16384

typedef float v4f __attribute__((ext_vector_type(4)));

#define WAIT_VM4()  asm volatile("s_waitcnt vmcnt(4)" ::: "memory")
#define WAIT_VM0()  asm volatile("s_waitcnt vmcnt(0)" ::: "memory")
#define RAW_BAR()   asm volatile("s_barrier" ::: "memory")
#define LGKM0_BAR() asm volatile("s_waitcnt lgkmcnt(0)\n\ts_barrier" ::: "memory")

__device__ __forceinline__ void async16(const void* g, void* l) {
  __builtin_amdgcn_global_load_lds(
      (const __attribute__((address_space(1))) char*)g,
      (__attribute__((address_space(3))) char*)l, 16, 0, 0);
}

// ================= shared device pieces (both paths) =================

// wave-per-row: norm, scales, fp8 e4m3 conversion (16x prescale)
__device__ __forceinline__ void prep_row(
    int row, int lane, const float* __restrict__ w, const float* __restrict__ x,
    char* __restrict__ wq8, char* __restrict__ xq8,
    float* __restrict__ fscale, float* __restrict__ ysqA, float* __restrict__ yrA,
    float* __restrict__ xsA, float* __restrict__ xrA)
{
  bool isW = row < Cn;
  const float* src = isW ? (w + (size_t)row * Dn) : (x + (size_t)(row - Cn) * Dn);
  const float4* s4 = (const float4*)src;
  float4 a = s4[lane * 2], b = s4[lane * 2 + 1];
  float ss = a.x * a.x + a.y * a.y + a.z * a.z + a.w * a.w
           + b.x * b.x + b.y * b.y + b.z * b.z + b.w * b.w;
  #pragma unroll
  for (int d = 1; d < 64; d <<= 1) ss += __shfl_xor(ss, d);

  int w0 = __builtin_amdgcn_cvt_pk_fp8_f32(a.x * 16.f, a.y * 16.f, 0, false);
  w0     = __builtin_amdgcn_cvt_pk_fp8_f32(a.z * 16.f, a.w * 16.f, w0, true);
  int w1 = __builtin_amdgcn_cvt_pk_fp8_f32(b.x * 16.f, b.y * 16.f, 0, false);
  w1     = __builtin_amdgcn_cvt_pk_fp8_f32(b.z * 16.f, b.w * 16.f, w1, true);
  char* dst = isW ? (wq8 + (size_t)row * Dn) : (xq8 + (size_t)(row - Cn) * Dn);
  ((int2*)dst)[lane] = make_int2(w0, w1);

  if (lane == 0) {
    if (isW) {
      float n = fmaxf(sqrtf(ss), 1e-7f);
      float t = tanhf(n);           // c=1: tanh(sqrt_c * norm)
      float tc = fminf(t, 0.95f);   // radius clip folded into scale
      fscale[row] = tc / n;
      float ys = tc * tc;
      ysqA[row] = ys;
      yrA[row] = 1.f / (1.f - fminf(ys, 1.f - 1e-5f));
    } else {
      int r = row - Cn;
      xsA[r] = ss;
      xrA[r] = 1.f / (1.f - fminf(ss, 1.f - 1e-5f));
    }
  }
}

// one 128x128 fp8 GEMM job: 2-buffer (32 KB) vmcnt pipeline (R8-proven ordering)
__device__ __forceinline__ void gemm_job(
    int job, int tid, char* lds,
    const char* __restrict__ xq8, const char* __restrict__ wq8,
    const float* __restrict__ fscale, const float* __restrict__ ysqA,
    const float* __restrict__ yrA, const float* __restrict__ xsA,
    const float* __restrict__ xrA, float* __restrict__ partials)
{
  const int xcd = job & 7;
  const int loc = job >> 3;
  const int mt  = loc & 15;
  const int nt  = (xcd << 4) | (loc >> 4);
  const int mBase = mt * 128;
  const int nBase = nt * 128;
  const int lane = tid & 63;
  const int wv = tid >> 6;
  const int quad = lane >> 4;
  const int l16 = lane & 15;
  const int waveM = wv >> 1;
  const int waveN = wv & 1;

  v4f acc[4][4];
  #pragma unroll
  for (int i = 0; i < 4; ++i)
    #pragma unroll
    for (int j = 0; j < 4; ++j)
      acc[i][j] = (v4f){0.f, 0.f, 0.f, 0.f};

  // staging: slot s -> r=s>>2, global chunk col (s&3)^((r>>1)&3)  (conflict-free)
  const int s0 = tid, s1 = tid + 256;
  const int r0 = s0 >> 2, c0 = (s0 & 3) ^ ((r0 >> 1) & 3);
  const int r1 = s1 >> 2, c1 = (s1 & 3) ^ ((r1 >> 1) & 3);
  const char* gA0 = xq8 + (size_t)(mBase + r0) * Dn + c0 * 16;
  const char* gA1 = xq8 + (size_t)(mBase + r1) * Dn + c1 * 16;
  const char* gW0 = wq8 + (size_t)(nBase + r0) * Dn + c0 * 16;
  const char* gW1 = wq8 + (size_t)(nBase + r1) * Dn + c1 * 16;
  const int lo0 = s0 * 16, lo1 = s1 * 16;

  const int kx = (l16 >> 1) & 3;
  int aoff[2], boff[2];
  #pragma unroll
  for (int s = 0; s < 2; ++s) {
    int chunk = (2 * s + (quad >> 1)) ^ kx;
    aoff[s] = (waveM * 64 + l16) * 64 + chunk * 16 + (quad & 1) * 8;
    boff[s] = (waveN * 64 + l16) * 64 + chunk * 16 + (quad & 1) * 8;
  }

  // prologue: tiles 0,1 -> buffers 0,1 (8 loads in flight)
  #pragma unroll
  for (int t = 0; t < 2; ++t) {
    char* Ab = lds + t * 16384;
    char* Wb = Ab + 8192;
    async16(gA0 + t * 64, Ab + lo0);
    async16(gA1 + t * 64, Ab + lo1);
    async16(gW0 + t * 64, Wb + lo0);
    async16(gW1 + t * 64, Wb + lo1);
  }

  #pragma unroll
  for (int kt = 0; kt < 8; ++kt) {
    const int cur = kt & 1;
    if (kt < 7) { WAIT_VM4(); } else { WAIT_VM0(); }  // tile kt landed (this wave)
    RAW_BAR();                                         // ...for all waves
    char* Ab = lds + cur * 16384;
    char* Wb = Ab + 8192;
    long af[4][2], bf[4][2];
    #pragma unroll
    for (int s = 0; s < 2; ++s) {
      #pragma unroll
      for (int i = 0; i < 4; ++i) af[i][s] = *(const long*)(Ab + aoff[s] + i * 1024);
      #pragma unroll
      for (int j = 0; j < 4; ++j) bf[j][s] = *(const long*)(Wb + boff[s] + j * 1024);
    }
    #pragma unroll
    for (int s = 0; s < 2; ++s)
      #pragma unroll
      for (int i = 0; i < 4; ++i)
        #pragma unroll
        for (int j = 0; j < 4; ++j)
          acc[i][j] = __builtin_amdgcn_mfma_f32_16x16x32_fp8_fp8(af[i][s], bf[j][s], acc[i][j], 0, 0, 0);
    LGKM0_BAR();  // all waves' reads of buf[cur] drained -> safe to rewrite
    if (kt + 2 < 8) {  // tile kt+2 into buf[cur]
      async16(gA0 + (kt + 2) * 64, Ab + lo0);
      async16(gA1 + (kt + 2) * 64, Ab + lo1);
      async16(gW0 + (kt + 2) * 64, Wb + lo0);
      async16(gW1 + (kt + 2) * 64, Wb + lo1);
    }
  }

  // epilogue: e^{+64}-scaled partial sums; 1/256 folds the 16x prescale
  float ysqj[4], yrj[4], gj[4];
  #pragma unroll
  for (int j = 0; j < 4; ++j) {
    int col = nBase + waveN * 64 + j * 16 + l16;
    gj[j] = -2.f * fscale[col] * (1.f / 256.f);
    ysqj[j] = ysqA[col];
    yrj[j] = yrA[col];
  }
  #pragma unroll
  for (int i = 0; i < 4; ++i) {
    #pragma unroll
    for (int r = 0; r < 4; ++r) {
      int row = mBase + waveM * 64 + i * 16 + quad * 4 + r;
      float xs = xsA[row];
      float xr2 = 2.f * xrA[row];
      float partial = 0.f;
      if (xs >= 0.99999f) {
        // clipped row: z large -> sims~=1/(2z), e^u ~= 1+u+u^2/2
        #pragma unroll
        for (int j = 0; j < 4; ++j) {
          float d = fmaxf(fmaf(gj[j], acc[i][j][r], xs + ysqj[j]), 0.f);
          float z = fmaf(d, xr2 * yrj[j], 1.f);
          float u = 64.f * __builtin_amdgcn_rcpf(z);
          partial += fmaf(u, fmaf(0.5f, u, 1.f), 1.f);
        }
      } else {
        #pragma unroll
        for (int j = 0; j < 4; ++j) {
          float d = fmaxf(fmaf(gj[j], acc[i][j][r], xs + ysqj[j]), 0.f);
          float z = fmaf(d, xr2 * yrj[j], 1.f);
          float sq = sqrtf(fmaf(z, z, -1.f));
          float u = 128.f * __builtin_amdgcn_rcpf(z + sq);
          partial += __expf(u);
        }
      }
      partial += __shfl_xor(partial, 1);
      partial += __shfl_xor(partial, 2);
      partial += __shfl_xor(partial, 4);
      partial += __shfl_xor(partial, 8);
      if (l16 == 0) partials[(size_t)row * 256 + nt * 2 + waveN] = partial;
    }
  }
}

// wave-per-row exact fp32 label fix; returns row term (valid on lane 0)
__device__ __forceinline__ float final_row_term(
    int row, int lane,
    const float* __restrict__ x, const float* __restrict__ w,
    const int* __restrict__ labels, const float* __restrict__ fscale,
    const float* __restrict__ ysqA, const float* __restrict__ yrA,
    const float* __restrict__ xsA, const float* __restrict__ xrA,
    const float* __restrict__ partials)
{
  const float* pr = partials + (size_t)row * 256;
  float sum = pr[lane] + pr[lane + 64] + pr[lane + 128] + pr[lane + 192];

  int lab = labels[row];
  const float4* xv = (const float4*)(x + (size_t)row * Dn);
  const float4* wv4 = (const float4*)(w + (size_t)lab * Dn);
  float4 a0 = xv[lane * 2], a1 = xv[lane * 2 + 1];
  float4 b0 = wv4[lane * 2], b1 = wv4[lane * 2 + 1];
  float dot = a0.x * b0.x + a0.y * b0.y + a0.z * b0.z + a0.w * b0.w
            + a1.x * b1.x + a1.y * b1.y + a1.z * b1.z + a1.w * b1.w;
  #pragma unroll
  for (int d = 1; d < 64; d <<= 1) {
    sum += __shfl_xor(sum, d);
    dot += __shfl_xor(dot, d);
  }

  float term = 0.f;
  if (lane == 0) {
    float xy = fscale[lab] * dot;
    float diff = fmaxf(xsA[row] + ysqA[lab] - 2.f * xy, 0.f);
    float z = fmaf(2.f * diff, xrA[row] * yrA[lab], 1.f);
    float sq = sqrtf(fmaf(z, z, -1.f));
    float sims = 1.f / (z + sq);
    float u_lab = 128.f * sims;
    float cosv = fmaf(2.f, sims, -1.f);
    float sine = sqrtf(fmaxf(fmaf(-cosv, cosv, 1.f), 1e-7f));
    float phi = (cosv > -0.8775825619f)
                    ? (cosv * 0.8775825619f - sine * 0.4794255386f)
                    : (cosv - 0.2397127693f);
    float e_lab = __expf(u_lab);
    float e_phi = __expf(fminf(64.f * phi + 64.f, 80.f));
    term = logf(sum - e_lab + e_phi) - 64.f * phi - 64.f;
  }
  return term;
}

// ================= path A: one cooperative dispatch, grid-size adaptive =================
// __launch_bounds__(256,3): 3 waves/EU -> reg cap ~170 (usage ~140 fits), LDS
// 3x32KB=96<=160 -> 3 blocks/CU co-residency. Grid = 256*min(3,maxPerCU).
// All phases stride by gridDim so 512 or 768 both correct; 768%8==0 keeps
// job&7 == bid&7 (XCD banding preserved for every t).
__global__ __launch_bounds__(256, 3) void fused_kernel(
    const float* __restrict__ w, const float* __restrict__ x,
    const int* __restrict__ labels,
    char* __restrict__ wq8, char* __restrict__ xq8,
    float* __restrict__ fscale, float* __restrict__ ysqA, float* __restrict__ yrA,
    float* __restrict__ xsA, float* __restrict__ xrA,
    float* __restrict__ partials, float* __restrict__ terms, float* __restrict__ out)
{
  __shared__ int4 ldsv[2048];  // 32 KB: buf{0,1} x [A 8K][W 8K]
  char* lds = (char*)ldsv;
  cg::grid_group grid = cg::this_grid();
  const int tid = threadIdx.x, lane = tid & 63, wv = tid >> 6;
  const int G = gridDim.x;
  const int gwv = (blockIdx.x << 2) | wv;   // global wave id
  const int wavesTotal = G << 2;

  // phase 1: prep (wave per row, grid-strided)
  for (int row = gwv; row < Cn + Bn; row += wavesTotal)
    prep_row(row, lane, w, x, wq8, xq8, fscale, ysqA, yrA, xsA, xrA);
  grid.sync();

  // phase 2: gemm jobs, grid-strided (blocks get ceil/floor(2048/G) jobs)
  #pragma unroll 1
  for (int job = blockIdx.x; job < 2048; job += G)
    gemm_job(job, tid, lds, xq8, wq8, fscale, ysqA, yrA, xsA, xrA, partials);
  grid.sync();

  // phase 3: label fix; one partial term-sum per block
  {
    float mysum = 0.f;
    for (int row = gwv; row < Bn; row += wavesTotal)
      mysum += final_row_term(row, lane, x, w, labels, fscale, ysqA, yrA, xsA, xrA, partials);
    float* red = (float*)lds;  // gemm LDS dead (job-end barrier drained all reads)
    if (lane == 0) red[wv] = mysum;  // lane 0 holds the valid term
    __syncthreads();
    if (tid == 0) terms[blockIdx.x] = red[0] + red[1] + red[2] + red[3];
  }
  grid.sync();

  // phase 4: block 0 reduces G terms
  if (blockIdx.x == 0) {
    float a = 0.f;
    for (int i = tid; i < G; i += 256) a += terms[i];
    #pragma unroll
    for (int d = 1; d < 64; d <<= 1) a += __shfl_xor(a, d);
    float* red = (float*)lds;
    if (lane == 0) red[wv] = a;
    __syncthreads();
    if (tid == 0) out[0] = (red[0] + red[1] + red[2] + red[3]) * (1.f / (float)Bn);
  }
}

// ================= path B: proven 4-dispatch fallback =================
__global__ __launch_bounds__(256) void prep_kernel(
    const float* __restrict__ w, const float* __restrict__ x,
    char* __restrict__ wq8, char* __restrict__ xq8,
    float* __restrict__ fscale, float* __restrict__ ysqA, float* __restrict__ yrA,
    float* __restrict__ xsA, float* __restrict__ xrA)
{
  int row = (blockIdx.x * 256 + threadIdx.x) >> 6;
  prep_row(row, threadIdx.x & 63, w, x, wq8, xq8, fscale, ysqA, yrA, xsA, xrA);
}

__global__ __launch_bounds__(256, 3) void gemm_kernel(
    const char* __restrict__ xq8, const char* __restrict__ wq8,
    const float* __restrict__ fscale, const float* __restrict__ ysqA,
    const float* __restrict__ yrA, const float* __restrict__ xsA,
    const float* __restrict__ xrA, float* __restrict__ partials)
{
  __shared__ int4 ldsv[2048];  // 32 KB
  gemm_job(blockIdx.x, threadIdx.x, (char*)ldsv, xq8, wq8, fscale, ysqA, yrA, xsA, xrA, partials);
}

__global__ __launch_bounds__(256) void final_kernel(
    const float* __restrict__ x, const float* __restrict__ w,
    const int* __restrict__ labels, const float* __restrict__ fscale,
    const float* __restrict__ ysqA, const float* __restrict__ yrA,
    const float* __restrict__ xsA, const float* __restrict__ xrA,
    const float* __restrict__ partials, float* __restrict__ out)
{
  int row = blockIdx.x * 4 + (threadIdx.x >> 6);
  float term = final_row_term(row, threadIdx.x & 63, x, w, labels, fscale,
                              ysqA, yrA, xsA, xrA, partials);
  __shared__ float red[4];
  if ((threadIdx.x & 63) == 0) red[threadIdx.x >> 6] = term;
  __syncthreads();
  if (threadIdx.x == 0)
    atomicAdd(out, (red[0] + red[1] + red[2] + red[3]) * (1.f / (float)Bn));
}

extern "C" void kernel_launch(void* const* d_in, const int* in_sizes, int n_in,
                              void* d_out, int out_size, void* d_ws, size_t ws_size,
                              hipStream_t stream) {
  (void)in_sizes; (void)n_in; (void)out_size; (void)ws_size;
  const float* emb = (const float*)d_in[0];
  const int* labels = (const int*)d_in[1];
  const float* weight = (const float*)d_in[2];
  float* out = (float*)d_out;

  char* p = (char*)d_ws;
  char* wq8 = p; p += (size_t)Cn * Dn;       // 8 MB fp8
  char* xq8 = p; p += (size_t)Bn * Dn;       // 1 MB fp8
  float* fscale = (float*)p; p += (size_t)Cn * 4;
  float* ysqA  = (float*)p; p += (size_t)Cn * 4;
  float* yrA   = (float*)p; p += (size_t)Cn * 4;
  float* xsA   = (float*)p; p += (size_t)Bn * 4;
  float* xrA   = (float*)p; p += (size_t)Bn * 4;
  float* partials = (float*)p; p += (size_t)Bn * 256 * 4;  // 2 MB, written-once
  float* terms = (float*)p; p += 768 * 4;                  // written-once

  // deterministic guard: cooperative support + occupancy-adaptive grid
  int dev = 0;
  hipGetDevice(&dev);
  int coopAttr = 0;
  hipDeviceGetAttribute(&coopAttr, hipDeviceAttributeCooperativeLaunch, dev);
  int maxPerCU = 0;
  hipOccupancyMaxActiveBlocksPerMultiprocessor(&maxPerCU, (const void*)fused_kernel, 256, 0);

  hipError_t le = hipErrorUnknown;
  if (coopAttr == 1 && maxPerCU >= 2) {
    int perCU = maxPerCU < 3 ? maxPerCU : 3;   // expect 3 -> grid 768
    dim3 grid(256 * perCU);
    void* args[] = {(void*)&weight, (void*)&emb, (void*)&labels,
                    (void*)&wq8, (void*)&xq8, (void*)&fscale, (void*)&ysqA,
                    (void*)&yrA, (void*)&xsA, (void*)&xrA,
                    (void*)&partials, (void*)&terms, (void*)&out};
    le = hipLaunchCooperativeKernel((const void*)fused_kernel, grid, dim3(256),
                                    args, 0, stream);
  }
  if (le != hipSuccess) {
    // proven multi-dispatch path (R10 structure)
    hipMemsetAsync(out, 0, sizeof(float), stream);
    prep_kernel<<<(Cn + Bn) / 4, 256, 0, stream>>>(weight, emb, wq8, xq8, fscale, ysqA, yrA, xsA, xrA);
    gemm_kernel<<<(Bn / 128) * (Cn / 128), 256, 0, stream>>>(
        xq8, wq8, fscale, ysqA, yrA, xsA, xrA, partials);
    final_kernel<<<Bn / 4, 256, 0, stream>>>(emb, weight, labels, fscale, ysqA, yrA, xsA, xrA, partials, out);
  }
}